// Round 6
// baseline (294.813 us; speedup 1.0000x reference)
//
#include <hip/hip_runtime.h>

#define B 16
#define P 32768
#define NG 128
#define KTOP 4
#define NBK 256                 // log-area buckets per batch
typedef unsigned long long u64;
typedef unsigned int u32;

// ---- bucket by log2(area): identical code in hist & scatter => deterministic ----
__device__ __forceinline__ int area_bucket(float ap) {
    float t = __log2f(ap);                    // ap in (4e-4, 0.09) -> t in (-11.3, -3.5)
    int k = (int)((t + 11.3f) * 32.0f);
    return k < 0 ? 0 : (k > NBK - 1 ? NBK - 1 : k);
}

// compare-exchange, descending on u64 keys
__device__ __forceinline__ void ce(u64 &x, u64 &y) {
    u64 a = x, b = y;
    bool gt = a > b;
    x = gt ? a : b;
    y = gt ? b : a;
}

// ---------------- preprocessing: counting sort of priors by area ----------------
__global__ void k_hist(const float* __restrict__ rois, u32* __restrict__ cursors) {
    int gid = blockIdx.x * 256 + threadIdx.x;          // 0 .. B*P-1
    int b = gid >> 15, i = gid & (P - 1);
    const float4* pv = (const float4*)(rois + ((size_t)(2 * b + 1)) * P * 4);
    float4 q = pv[i];
    float ap = (q.z - q.x) * (q.w - q.y);
    atomicAdd(&cursors[b * NBK + area_bucket(ap)], 1u);
}

__global__ void k_scan(u32* __restrict__ cursors) {    // 16 blocks x 64 threads
    int b = blockIdx.x, l = threadIdx.x;
    u32* row = cursors + b * NBK;
    u32 c0 = row[l*4+0], c1 = row[l*4+1], c2 = row[l*4+2], c3 = row[l*4+3];
    u32 s = c0 + c1 + c2 + c3, incl = s;
    #pragma unroll
    for (int d = 1; d < 64; d <<= 1) {
        u32 v = __shfl_up(incl, d, 64);
        if (l >= d) incl += v;
    }
    u32 excl = incl - s;
    row[l*4+0] = excl;
    row[l*4+1] = excl + c0;
    row[l*4+2] = excl + c0 + c1;
    row[l*4+3] = excl + c0 + c1 + c2;
}

__global__ void k_scatter(const float* __restrict__ rois, u32* __restrict__ cursors,
                          float4* __restrict__ sbox, u32* __restrict__ sidx,
                          float* __restrict__ sap) {
    int gid = blockIdx.x * 256 + threadIdx.x;
    int b = gid >> 15, i = gid & (P - 1);
    const float4* pv = (const float4*)(rois + ((size_t)(2 * b + 1)) * P * 4);
    float4 q = pv[i];
    float ap = (q.z - q.x) * (q.w - q.y);
    u32 slot = atomicAdd(&cursors[b * NBK + area_bucket(ap)], 1u);  // order irrelevant: u64 keys
    size_t pos = (size_t)b * P + slot;
    sbox[pos] = q;
    sidx[pos] = (u32)i;
    sap[pos]  = ap;
}

// ---------------- main: area-screened exact top-4 per truth ----------------
__global__ __launch_bounds__(256, 8)
void k_main(const float* __restrict__ targets, const float4* __restrict__ sbox,
            const u32* __restrict__ sidx, const float* __restrict__ sap,
            u64* __restrict__ cand)
{
    #pragma clang fp contract(off)

    const int blk = blockIdx.x;                       // 2048
    const int b   = ((blk & 7) << 1) | ((blk >> 3) & 1);  // 2 batches per XCD
    const int g   = blk >> 4;

    const float* tp = targets + ((size_t)(b * NG + g)) * 4;
    const float t0 = tp[0], t1 = tp[1], t2 = tp[2], t3 = tp[3];
    const float areaT = (t2 - t0) * (t3 - t1);

    const float4* __restrict__ boxb = sbox + (size_t)b * P;
    const u32*    __restrict__ idxb = sidx + (size_t)b * P;
    const float*  __restrict__ apb  = sap  + (size_t)b * P;

    u64 k0 = 0, k1 = 0, k2 = 0, k3 = 0;
    float v3f = -1.0f;                                // value part of k3 (screen threshold)

    for (int i = threadIdx.x; i < P; i += 256) {
        float ap = apb[i];
        // conservative screen: iou <= min/max; margin 1e-4 >> all f32 rounding,
        // so equal-value/tie candidates always pass. v3f<=0 => always pass.
        float mn = fminf(areaT, ap), mx = fmaxf(areaT, ap);
        bool pass = mn * 1.0001f > v3f * mx;
        if (__any(pass)) {
            float4 q = boxb[i];
            u32 oi = idxb[i];
            // IoU bit-exact vs numpy fp32 (no contraction, IEEE div, same op order)
            float ltx = fmaxf(t0, q.x), lty = fmaxf(t1, q.y);
            float rbx = fminf(t2, q.z), rby = fminf(t3, q.w);
            float wx = fmaxf(rbx - ltx, 0.0f);
            float wy = fmaxf(rby - lty, 0.0f);
            float inter = wx * wy;
            float iou = inter / ((areaT + ap) - inter);

            // total-order key: higher iou wins, ties -> lower original index
            u64 x = ((u64)__float_as_uint(iou) << 32) | (u32)(~oi);

            bool g0 = x > k0, g1 = x > k1, g2 = x > k2, g3 = x > k3;
            u64 n3 = g2 ? k2 : (g3 ? x : k3);
            u64 n2 = g1 ? k1 : (g2 ? x : k2);
            u64 n1 = g0 ? k0 : (g1 ? x : k1);
            u64 n0 = g0 ? x  : k0;
            k0 = n0; k1 = n1; k2 = n2; k3 = n3;
            v3f = __uint_as_float((u32)(k3 >> 32));
        }
    }

    // per-wave merge of sorted-4 lists (bitonic 8->4), barrier-free
    #pragma unroll
    for (int d = 32; d >= 1; d >>= 1) {
        u64 n0 = __shfl_down(k0, d, 64);
        u64 n1 = __shfl_down(k1, d, 64);
        u64 n2 = __shfl_down(k2, d, 64);
        u64 n3 = __shfl_down(k3, d, 64);
        ce(k0, n3); ce(k1, n2); ce(k2, n1); ce(k3, n0);
        ce(k0, k2); ce(k1, k3); ce(k0, k1); ce(k2, k3);
    }

    const int lane = threadIdx.x & 63;
    const int wv   = threadIdx.x >> 6;
    if (lane == 0) {
        u64* dst = cand + ((size_t)(b * NG + g)) * 16 + wv * 4;
        dst[0] = k0; dst[1] = k1; dst[2] = k2; dst[3] = k3;
    }
}

// ---------------- phase 2: merge 16 candidates per truth, encode ----------------
__global__ __launch_bounds__(256)
void k_phase2(const float* __restrict__ rois, const float* __restrict__ targets,
              const u64* __restrict__ cand, float* __restrict__ out, int ntruth)
{
    #pragma clang fp contract(off)

    const int tg = blockIdx.x * 256 + threadIdx.x;
    if (tg >= ntruth) return;
    const int b = tg >> 7;

    const u64* c = cand + (size_t)tg * 16;
    u64 k0 = 0, k1 = 0, k2 = 0, k3 = 0;
    #pragma unroll
    for (int j = 0; j < 16; ++j) {
        u64 x = c[j];
        bool g0 = x > k0, g1 = x > k1, g2 = x > k2, g3 = x > k3;
        u64 n3 = g2 ? k2 : (g3 ? x : k3);
        u64 n2 = g1 ? k1 : (g2 ? x : k2);
        u64 n1 = g0 ? k0 : (g1 ? x : k1);
        u64 n0 = g0 ? x  : k0;
        k0 = n0; k1 = n1; k2 = n2; k3 = n3;
    }

    const float* tp = targets + (size_t)tg * 4;
    const float t0 = tp[0], t1 = tp[1], t2 = tp[2], t3 = tp[3];
    const float gcx = (t0 + t2) * 0.5f;
    const float gcy = (t1 + t3) * 0.5f;
    const float gw  = t2 - t0;
    const float gh  = t3 - t1;

    const float4* __restrict__ pv =
        (const float4*)(rois + ((size_t)(2 * b + 1)) * P * 4);
    float4* __restrict__ o4 = (float4*)out;

    u64 ks[KTOP] = {k0, k1, k2, k3};
    #pragma unroll
    for (int k = 0; k < KTOP; ++k) {
        int idx = (int)(~(u32)ks[k]) & (P - 1);   // decode original prior index
        float4 q = pv[idx];
        float pcx = (q.x + q.z) * 0.5f;
        float pcy = (q.y + q.w) * 0.5f;
        float pw  = q.z - q.x;
        float ph  = q.w - q.y;
        float4 r;
        r.x = (gcx - pcx) / (0.1f * pw);
        r.y = (gcy - pcy) / (0.1f * ph);
        r.z = logf(gw / pw) / 0.2f;
        r.w = logf(gh / ph) / 0.2f;
        o4[(size_t)tg * KTOP + k] = r;
    }
}

extern "C" void kernel_launch(void* const* d_in, const int* in_sizes, int n_in,
                              void* d_out, int out_size, void* d_ws, size_t ws_size,
                              hipStream_t stream) {
    const float* rois    = (const float*)d_in[0];
    const float* targets = (const float*)d_in[1];
    float* out = (float*)d_out;

    char* w = (char*)d_ws;
    float4* sbox   = (float4*)(w);                            //  8 MB
    u32*    sidx   = (u32*)  (w + (size_t)B * P * 16);        //  2 MB
    float*  sap    = (float*)(w + (size_t)B * P * 20);        //  2 MB
    u64*    cand   = (u64*)  (w + (size_t)B * P * 24);        // 256 KB
    u32*    cursors= (u32*)  (w + (size_t)B * P * 24 + (size_t)B * NG * 16 * 8);  // 16 KB

    const int ntruth = B * NG;                                // 2048

    hipMemsetAsync(cursors, 0, B * NBK * sizeof(u32), stream);
    k_hist   <<<dim3(B * P / 256), dim3(256), 0, stream>>>(rois, cursors);
    k_scan   <<<dim3(B),           dim3(64),  0, stream>>>(cursors);
    k_scatter<<<dim3(B * P / 256), dim3(256), 0, stream>>>(rois, cursors, sbox, sidx, sap);
    k_main   <<<dim3(ntruth),      dim3(256), 0, stream>>>(targets, sbox, sidx, sap, cand);
    k_phase2 <<<dim3((ntruth + 255) / 256), dim3(256), 0, stream>>>(rois, targets, cand, out, ntruth);
}

// Round 7
// 182.315 us; speedup vs baseline: 1.6170x; 1.6170x over previous
//
#include <hip/hip_runtime.h>

#define B 16
#define P 32768
#define NG 128
#define KTOP 4
#define NBK 256                 // log-area buckets per batch
typedef unsigned long long u64;
typedef unsigned int u32;

// bucket by log2(area); identical code in sort & range lookup; v_log_f32 monotone
__device__ __forceinline__ int area_bucket(float ap) {
    float t = __log2f(ap);
    int k = (int)((t + 11.3f) * 32.0f);
    return k < 0 ? 0 : (k > NBK - 1 ? NBK - 1 : k);
}

// compare-exchange, descending, u64
__device__ __forceinline__ void ceu(u64 &x, u64 &y) {
    u64 a = x, b = y;
    bool gt = a > b;
    x = gt ? a : b;
    y = gt ? b : a;
}
// compare-exchange, descending, float
__device__ __forceinline__ void cef(float &x, float &y) {
    float h = fmaxf(x, y), l = fminf(x, y);
    x = h; y = l;
}

// ---------- kernel 1: per-batch counting sort of priors by area (fused) ----------
__global__ __launch_bounds__(1024)
void k_sort(const float* __restrict__ rois,
            float4* __restrict__ sbox, u32* __restrict__ sidx, u32* __restrict__ off)
{
    #pragma clang fp contract(off)
    const int b = blockIdx.x;
    const int tid = threadIdx.x;
    __shared__ u32 hist[NBK];

    if (tid < NBK) hist[tid] = 0;
    __syncthreads();

    const float4* __restrict__ pv = (const float4*)(rois + ((size_t)(2 * b + 1)) * P * 4);

    for (int it = 0; it < P / 1024; ++it) {
        float4 q = pv[tid + it * 1024];
        float ap = (q.z - q.x) * (q.w - q.y);
        atomicAdd(&hist[area_bucket(ap)], 1u);
    }
    __syncthreads();

    // exclusive scan of 256 bins by one wave (4 bins/lane)
    if (tid < 64) {
        int l = tid;
        u32 c0 = hist[l*4+0], c1 = hist[l*4+1], c2 = hist[l*4+2], c3 = hist[l*4+3];
        u32 s = c0 + c1 + c2 + c3, incl = s;
        #pragma unroll
        for (int d = 1; d < 64; d <<= 1) {
            u32 v = __shfl_up(incl, d, 64);
            if (l >= d) incl += v;
        }
        u32 excl = incl - s;
        hist[l*4+0] = excl;
        hist[l*4+1] = excl + c0;
        hist[l*4+2] = excl + c0 + c1;
        hist[l*4+3] = excl + c0 + c1 + c2;
    }
    __syncthreads();

    // persist offsets for the range lookup
    if (tid < NBK) off[b * (NBK + 1) + tid] = hist[tid];
    if (tid == 0)  off[b * (NBK + 1) + NBK] = P;
    __syncthreads();

    // scatter (order within bucket nondeterministic -> harmless: u64 keys later)
    for (int it = 0; it < P / 1024; ++it) {
        int i = tid + it * 1024;
        float4 q = pv[i];
        float ap = (q.z - q.x) * (q.w - q.y);
        u32 slot = atomicAdd(&hist[area_bucket(ap)], 1u);
        sbox[(size_t)b * P + slot] = q;
        sidx[(size_t)b * P + slot] = (u32)i;
    }
}

// ---------- kernel 2: LB subsample + range scan + exact top-4 + encode ----------
__global__ __launch_bounds__(256, 8)
void k_main(const float* __restrict__ rois, const float* __restrict__ targets,
            const float4* __restrict__ sbox, const u32* __restrict__ sidx,
            const u32* __restrict__ off, float* __restrict__ out)
{
    #pragma clang fp contract(off)

    const int blk = blockIdx.x;                           // 2048
    const int b   = ((blk & 7) << 1) | ((blk >> 3) & 1);  // 2 batches per XCD
    const int g   = blk >> 4;
    const int tid = threadIdx.x;
    const int lane = tid & 63, wv = tid >> 6;

    const float* tp = targets + ((size_t)(b * NG + g)) * 4;
    const float t0 = tp[0], t1 = tp[1], t2 = tp[2], t3 = tp[3];
    const float areaT = (t2 - t0) * (t3 - t1);

    const float4* __restrict__ boxb = sbox + (size_t)b * P;
    const u32*    __restrict__ idxb = sidx + (size_t)b * P;
    const u32*    __restrict__ offb = off + b * (NBK + 1);

    __shared__ float sf[4][4];
    __shared__ u64   sm[4][4];
    __shared__ int   sh_lo, sh_hi;

    // ---- stage 0: exact-IoU subsample (2048 priors) -> LB = 4th best value ----
    float w0 = -1.f, w1 = -1.f, w2 = -1.f, w3 = -1.f;
    #pragma unroll
    for (int it = 0; it < 8; ++it) {
        int pos = (tid + it * 256) * 16;                  // stride-16 over sorted array
        float4 q = boxb[pos];
        float ap = (q.z - q.x) * (q.w - q.y);
        float ltx = fmaxf(t0, q.x), lty = fmaxf(t1, q.y);
        float rbx = fminf(t2, q.z), rby = fminf(t3, q.w);
        float wx = fmaxf(rbx - ltx, 0.0f);
        float wy = fmaxf(rby - lty, 0.0f);
        float inter = wx * wy;
        float iou = inter / ((areaT + ap) - inter);
        // value-only sorted-desc insert (min/max chain)
        float x = iou, h;
        h = fmaxf(w0, x); x = fminf(w0, x); w0 = h;
        h = fmaxf(w1, x); x = fminf(w1, x); w1 = h;
        h = fmaxf(w2, x); x = fminf(w2, x); w2 = h;
        w3 = fmaxf(w3, x);
    }
    #pragma unroll
    for (int d = 32; d >= 1; d >>= 1) {
        float n0 = __shfl_down(w0, d, 64);
        float n1 = __shfl_down(w1, d, 64);
        float n2 = __shfl_down(w2, d, 64);
        float n3 = __shfl_down(w3, d, 64);
        cef(w0, n3); cef(w1, n2); cef(w2, n1); cef(w3, n0);
        cef(w0, w2); cef(w1, w3); cef(w0, w1); cef(w2, w3);
    }
    if (lane == 0) { sf[wv][0] = w0; sf[wv][1] = w1; sf[wv][2] = w2; sf[wv][3] = w3; }
    __syncthreads();

    if (tid == 0) {
        float m0 = -1.f, m1 = -1.f, m2 = -1.f, m3 = -1.f;
        #pragma unroll
        for (int j = 0; j < 16; ++j) {
            float x = sf[j >> 2][j & 3], h;
            h = fmaxf(m0, x); x = fminf(m0, x); m0 = h;
            h = fmaxf(m1, x); x = fminf(m1, x); m1 = h;
            h = fmaxf(m2, x); x = fminf(m2, x); m2 = h;
            m3 = fmaxf(m3, x);
        }
        float lb_eff = m3 * 0.999f;                       // margin >> all f32 rounding
        int lo = 0, hi = P;
        if (lb_eff > 0.0f) {
            float amin = areaT * lb_eff;
            float amax = areaT / lb_eff;
            int bl = area_bucket(amin) - 1; if (bl < 0) bl = 0;
            int bh = area_bucket(amax) + 1; if (bh > NBK - 1) bh = NBK - 1;
            lo = (int)offb[bl];
            hi = (int)offb[bh + 1];
        }
        sh_lo = lo; sh_hi = hi;
    }
    __syncthreads();
    const int lo = sh_lo, hi = sh_hi;

    // ---- stage 1: exact top-4 over the provably-sufficient range ----
    u64 k0 = 0, k1 = 0, k2 = 0, k3 = 0;
    for (int pos = lo + tid; pos < hi; pos += 256) {
        float4 q = boxb[pos];
        u32 oi = idxb[pos];
        float ap = (q.z - q.x) * (q.w - q.y);
        // IoU bit-exact vs numpy fp32 (no contraction, IEEE div, same op order)
        float ltx = fmaxf(t0, q.x), lty = fmaxf(t1, q.y);
        float rbx = fminf(t2, q.z), rby = fminf(t3, q.w);
        float wx = fmaxf(rbx - ltx, 0.0f);
        float wy = fmaxf(rby - lty, 0.0f);
        float inter = wx * wy;
        float iou = inter / ((areaT + ap) - inter);

        u64 x = ((u64)__float_as_uint(iou) << 32) | (u32)(~oi);  // ties -> lower index
        bool g0 = x > k0, g1 = x > k1, g2 = x > k2, g3 = x > k3;
        u64 n3 = g2 ? k2 : (g3 ? x : k3);
        u64 n2 = g1 ? k1 : (g2 ? x : k2);
        u64 n1 = g0 ? k0 : (g1 ? x : k1);
        u64 n0 = g0 ? x  : k0;
        k0 = n0; k1 = n1; k2 = n2; k3 = n3;
    }

    #pragma unroll
    for (int d = 32; d >= 1; d >>= 1) {
        u64 n0 = __shfl_down(k0, d, 64);
        u64 n1 = __shfl_down(k1, d, 64);
        u64 n2 = __shfl_down(k2, d, 64);
        u64 n3 = __shfl_down(k3, d, 64);
        ceu(k0, n3); ceu(k1, n2); ceu(k2, n1); ceu(k3, n0);
        ceu(k0, k2); ceu(k1, k3); ceu(k0, k1); ceu(k2, k3);
    }
    if (lane == 0) { sm[wv][0] = k0; sm[wv][1] = k1; sm[wv][2] = k2; sm[wv][3] = k3; }
    __syncthreads();

    if (tid == 0) {
        u64 f0 = 0, f1 = 0, f2 = 0, f3 = 0;
        #pragma unroll
        for (int j = 0; j < 16; ++j) {
            u64 x = sm[j >> 2][j & 3];
            bool g0 = x > f0, g1 = x > f1, g2 = x > f2, g3 = x > f3;
            u64 n3 = g2 ? f2 : (g3 ? x : f3);
            u64 n2 = g1 ? f1 : (g2 ? x : f2);
            u64 n1 = g0 ? f0 : (g1 ? x : f1);
            u64 n0 = g0 ? x  : f0;
            f0 = n0; f1 = n1; f2 = n2; f3 = n3;
        }
        const float gcx = (t0 + t2) * 0.5f;
        const float gcy = (t1 + t3) * 0.5f;
        const float gw  = t2 - t0;
        const float gh  = t3 - t1;
        const float4* __restrict__ pv =
            (const float4*)(rois + ((size_t)(2 * b + 1)) * P * 4);
        float4* __restrict__ o4 = (float4*)out;

        u64 ks[KTOP] = {f0, f1, f2, f3};
        #pragma unroll
        for (int k = 0; k < KTOP; ++k) {
            int idx = (int)(~(u32)ks[k]) & (P - 1);       // decode original prior index
            float4 q = pv[idx];
            float pcx = (q.x + q.z) * 0.5f;
            float pcy = (q.y + q.w) * 0.5f;
            float pw  = q.z - q.x;
            float ph  = q.w - q.y;
            float4 r;
            r.x = (gcx - pcx) / (0.1f * pw);
            r.y = (gcy - pcy) / (0.1f * ph);
            r.z = logf(gw / pw) / 0.2f;
            r.w = logf(gh / ph) / 0.2f;
            o4[((size_t)(b * NG + g)) * KTOP + k] = r;
        }
    }
}

extern "C" void kernel_launch(void* const* d_in, const int* in_sizes, int n_in,
                              void* d_out, int out_size, void* d_ws, size_t ws_size,
                              hipStream_t stream) {
    const float* rois    = (const float*)d_in[0];
    const float* targets = (const float*)d_in[1];
    float* out = (float*)d_out;

    char* w = (char*)d_ws;
    float4* sbox = (float4*)(w);                               // 8 MB
    u32*    sidx = (u32*)  (w + (size_t)B * P * 16);           // 2 MB
    u32*    off  = (u32*)  (w + (size_t)B * P * 20);           // 16.4 KB

    k_sort<<<dim3(B),        dim3(1024), 0, stream>>>(rois, sbox, sidx, off);
    k_main<<<dim3(B * NG),   dim3(256),  0, stream>>>(rois, targets, sbox, sidx, off, out);
}

// Round 8
// 138.417 us; speedup vs baseline: 2.1299x; 1.3171x over previous
//
#include <hip/hip_runtime.h>

#define B 16
#define P 32768
#define NG 128
#define KTOP 4
#define NBX 32
#define NBY 32
#define NBB (NBX * NBY)          // 1024 bins per batch
#define SUB 16                   // sub-blocks per batch for sort
#define SUBP (P / SUB)           // 2048 priors per sort block
typedef unsigned long long u64;
typedef unsigned int u32;

// bucket map for left/bottom edge; domain ~(-0.05, 0.89); monotone non-decreasing
__device__ __forceinline__ int bkt(float v) {
    int k = (int)((v + 0.08f) * 32.0f);
    return k < 0 ? 0 : (k > 31 ? 31 : k);
}

// compare-exchange, descending, u64 / float
__device__ __forceinline__ void ceu(u64 &x, u64 &y) {
    u64 a = x, b = y; bool gt = a > b;
    x = gt ? a : b;  y = gt ? b : a;
}
__device__ __forceinline__ void cef(float &x, float &y) {
    float h = fmaxf(x, y), l = fminf(x, y); x = h; y = l;
}

// ---------- kernel A: per-(batch,subblock) local histogram + batch wh-max ----------
__global__ __launch_bounds__(256)
void k_hist(const float* __restrict__ rois, u32* __restrict__ cnt, u32* __restrict__ whmax)
{
    const int b = blockIdx.x >> 4, sub = blockIdx.x & 15;
    const int tid = threadIdx.x;
    __shared__ u32 h[NBB];
    for (int j = tid; j < NBB; j += 256) h[j] = 0;
    __syncthreads();

    const float4* __restrict__ pv = (const float4*)(rois + ((size_t)(2 * b + 1)) * P * 4);
    float wmax = 0.f, hmax = 0.f;
    #pragma unroll
    for (int it = 0; it < SUBP / 256; ++it) {
        float4 q = pv[sub * SUBP + it * 256 + tid];
        atomicAdd(&h[bkt(q.x) * NBY + bkt(q.y)], 1u);
        wmax = fmaxf(wmax, q.z - q.x);
        hmax = fmaxf(hmax, q.w - q.y);
    }
    __syncthreads();
    for (int j = tid; j < NBB; j += 256) cnt[(size_t)blockIdx.x * NBB + j] = h[j];

    #pragma unroll
    for (int d = 32; d >= 1; d >>= 1) {
        wmax = fmaxf(wmax, __shfl_down(wmax, d, 64));
        hmax = fmaxf(hmax, __shfl_down(hmax, d, 64));
    }
    if ((tid & 63) == 0) {   // positive floats: bit-compare == value-compare
        atomicMax(&whmax[b * 2 + 0], __float_as_uint(wmax));
        atomicMax(&whmax[b * 2 + 1], __float_as_uint(hmax));
    }
}

// ---------- kernel B: per-batch scan -> per-subblock cursors + bin offsets ----------
__global__ __launch_bounds__(1024)
void k_scan(u32* __restrict__ cnt, u32* __restrict__ off)
{
    const int b = blockIdx.x, j = threadIdx.x;       // j = bin
    const int lane = j & 63, wv = j >> 6;
    u32 c[SUB], s = 0;
    #pragma unroll
    for (int k = 0; k < SUB; ++k) { c[k] = cnt[(size_t)(b * SUB + k) * NBB + j]; s += c[k]; }

    __shared__ u32 wsum[16];
    u32 incl = s;
    #pragma unroll
    for (int d = 1; d < 64; d <<= 1) {
        u32 v = __shfl_up(incl, d, 64);
        if (lane >= d) incl += v;
    }
    if (lane == 63) wsum[wv] = incl;
    __syncthreads();
    if (j < 16) {
        u32 t = wsum[j];
        #pragma unroll
        for (int d = 1; d < 16; d <<= 1) {
            u32 v = __shfl_up(t, d, 64);
            if (lane >= d) t += v;
        }
        wsum[j] = t;                                  // inclusive wave totals
    }
    __syncthreads();
    u32 excl = (wv ? wsum[wv - 1] : 0u) + incl - s;   // batch-local bin base

    u32 run = excl;
    #pragma unroll
    for (int k = 0; k < SUB; ++k) { cnt[(size_t)(b * SUB + k) * NBB + j] = run; run += c[k]; }
    off[b * (NBB + 1) + j] = excl;
    if (j == 0) off[b * (NBB + 1) + NBB] = P;
}

// ---------- kernel C: scatter into (bx,by)-sorted order ----------
__global__ __launch_bounds__(256)
void k_scat(const float* __restrict__ rois, const u32* __restrict__ cnt,
            float4* __restrict__ sbox, u32* __restrict__ sidx)
{
    const int b = blockIdx.x >> 4, sub = blockIdx.x & 15;
    const int tid = threadIdx.x;
    __shared__ u32 cur[NBB];
    for (int j = tid; j < NBB; j += 256) cur[j] = cnt[(size_t)blockIdx.x * NBB + j];
    __syncthreads();

    const float4* __restrict__ pv = (const float4*)(rois + ((size_t)(2 * b + 1)) * P * 4);
    #pragma unroll
    for (int it = 0; it < SUBP / 256; ++it) {
        int i = sub * SUBP + it * 256 + tid;
        float4 q = pv[i];
        u32 slot = atomicAdd(&cur[bkt(q.x) * NBY + bkt(q.y)], 1u);  // order irrelevant: u64 keys
        sbox[(size_t)b * P + slot] = q;
        sidx[(size_t)b * P + slot] = (u32)i;
    }
}

// ---------- kernel D: LB subsample + windowed exact top-4 + encode ----------
__global__ __launch_bounds__(256, 8)
void k_main(const float* __restrict__ rois, const float* __restrict__ targets,
            const float4* __restrict__ sbox, const u32* __restrict__ sidx,
            const u32* __restrict__ off, const u32* __restrict__ whmax,
            float* __restrict__ out)
{
    #pragma clang fp contract(off)

    const int blk = blockIdx.x;                           // 2048
    const int b   = ((blk & 7) << 1) | ((blk >> 3) & 1);  // 2 batches per XCD
    const int g   = blk >> 4;
    const int tid = threadIdx.x;
    const int lane = tid & 63, wv = tid >> 6;

    const float* tp = targets + ((size_t)(b * NG + g)) * 4;
    const float t0 = tp[0], t1 = tp[1], t2 = tp[2], t3 = tp[3];
    const float areaT = (t2 - t0) * (t3 - t1);
    const float gw = t2 - t0, gh = t3 - t1;

    const float4* __restrict__ boxb = sbox + (size_t)b * P;
    const u32*    __restrict__ idxb = sidx + (size_t)b * P;
    const u32*    __restrict__ offb = off + b * (NBB + 1);

    __shared__ float sf[4][4];
    __shared__ u64   sm[4][4];
    __shared__ int   seg_lo[NBX], seg_hi[NBX];
    __shared__ int   sh_nseg;

    // ---- stage 0: exact-IoU subsample (1024 boxes, stride 32) -> LB ----
    float w0 = -1.f, w1 = -1.f, w2 = -1.f, w3 = -1.f;
    #pragma unroll
    for (int it = 0; it < 4; ++it) {
        float4 q = boxb[(tid + it * 256) * 32];
        float ap = (q.z - q.x) * (q.w - q.y);
        float ltx = fmaxf(t0, q.x), lty = fmaxf(t1, q.y);
        float rbx = fminf(t2, q.z), rby = fminf(t3, q.w);
        float wx = fmaxf(rbx - ltx, 0.0f);
        float wy = fmaxf(rby - lty, 0.0f);
        float inter = wx * wy;
        float iou = inter / ((areaT + ap) - inter);
        float x = iou, h;
        h = fmaxf(w0, x); x = fminf(w0, x); w0 = h;
        h = fmaxf(w1, x); x = fminf(w1, x); w1 = h;
        h = fmaxf(w2, x); x = fminf(w2, x); w2 = h;
        w3 = fmaxf(w3, x);
    }
    #pragma unroll
    for (int d = 32; d >= 1; d >>= 1) {
        float n0 = __shfl_down(w0, d, 64);
        float n1 = __shfl_down(w1, d, 64);
        float n2 = __shfl_down(w2, d, 64);
        float n3 = __shfl_down(w3, d, 64);
        cef(w0, n3); cef(w1, n2); cef(w2, n1); cef(w3, n0);
        cef(w0, w2); cef(w1, w3); cef(w0, w1); cef(w2, w3);
    }
    if (lane == 0) { sf[wv][0] = w0; sf[wv][1] = w1; sf[wv][2] = w2; sf[wv][3] = w3; }
    __syncthreads();

    if (tid == 0) {
        float m0 = -1.f, m1 = -1.f, m2 = -1.f, m3 = -1.f;
        #pragma unroll
        for (int j = 0; j < 16; ++j) {
            float x = sf[j >> 2][j & 3], h;
            h = fmaxf(m0, x); x = fminf(m0, x); m0 = h;
            h = fmaxf(m1, x); x = fminf(m1, x); m1 = h;
            h = fmaxf(m2, x); x = fminf(m2, x); m2 = h;
            m3 = fmaxf(m3, x);
        }
        int nseg = 0;
        if (m3 > 1e-6f) {
            float lb = m3 * 0.999f;                       // margin >> all fp32 rounding
            float wmaxb = __uint_as_float(whmax[b * 2 + 0]);
            float hmaxb = __uint_as_float(whmax[b * 2 + 1]);
            // necessary conditions for iou >= lb (see round notes): edge windows
            int bxlo = bkt(t0 + lb * gw - wmaxb) - 1; if (bxlo < 0) bxlo = 0;
            int bxhi = bkt(t2 - lb * gw) + 1;          if (bxhi > 31) bxhi = 31;
            int bylo = bkt(t1 + lb * gh - hmaxb) - 1;  if (bylo < 0) bylo = 0;
            int byhi = bkt(t3 - lb * gh) + 1;          if (byhi > 31) byhi = 31;
            for (int bx = bxlo; bx <= bxhi; ++bx) {
                int lo = (int)offb[bx * NBY + bylo];
                int hi = (int)offb[bx * NBY + byhi + 1];
                if (hi > lo) { seg_lo[nseg] = lo; seg_hi[nseg] = hi; ++nseg; }
            }
        }
        if (nseg == 0) { seg_lo[0] = 0; seg_hi[0] = P; nseg = 1; }   // fallback: full scan
        sh_nseg = nseg;
    }
    __syncthreads();
    const int nseg = sh_nseg;

    // ---- stage 1: exact top-4 over the provably-sufficient segments ----
    u64 k0 = 0, k1 = 0, k2 = 0, k3 = 0;
    for (int s = 0; s < nseg; ++s) {
        const int lo = seg_lo[s], hi = seg_hi[s];
        for (int pos = lo + tid; pos < hi; pos += 256) {
            float4 q = boxb[pos];
            u32 oi = idxb[pos];
            float ap = (q.z - q.x) * (q.w - q.y);
            // IoU bit-exact vs numpy fp32 (no contraction, IEEE div, same op order)
            float ltx = fmaxf(t0, q.x), lty = fmaxf(t1, q.y);
            float rbx = fminf(t2, q.z), rby = fminf(t3, q.w);
            float wx = fmaxf(rbx - ltx, 0.0f);
            float wy = fmaxf(rby - lty, 0.0f);
            float inter = wx * wy;
            float iou = inter / ((areaT + ap) - inter);

            u64 x = ((u64)__float_as_uint(iou) << 32) | (u32)(~oi);  // ties -> lower index
            bool g0 = x > k0, g1 = x > k1, g2 = x > k2, g3 = x > k3;
            u64 n3 = g2 ? k2 : (g3 ? x : k3);
            u64 n2 = g1 ? k1 : (g2 ? x : k2);
            u64 n1 = g0 ? k0 : (g1 ? x : k1);
            u64 n0 = g0 ? x  : k0;
            k0 = n0; k1 = n1; k2 = n2; k3 = n3;
        }
    }

    #pragma unroll
    for (int d = 32; d >= 1; d >>= 1) {
        u64 n0 = __shfl_down(k0, d, 64);
        u64 n1 = __shfl_down(k1, d, 64);
        u64 n2 = __shfl_down(k2, d, 64);
        u64 n3 = __shfl_down(k3, d, 64);
        ceu(k0, n3); ceu(k1, n2); ceu(k2, n1); ceu(k3, n0);
        ceu(k0, k2); ceu(k1, k3); ceu(k0, k1); ceu(k2, k3);
    }
    if (lane == 0) { sm[wv][0] = k0; sm[wv][1] = k1; sm[wv][2] = k2; sm[wv][3] = k3; }
    __syncthreads();

    if (tid == 0) {
        u64 f0 = 0, f1 = 0, f2 = 0, f3 = 0;
        #pragma unroll
        for (int j = 0; j < 16; ++j) {
            u64 x = sm[j >> 2][j & 3];
            bool g0 = x > f0, g1 = x > f1, g2 = x > f2, g3 = x > f3;
            u64 n3 = g2 ? f2 : (g3 ? x : f3);
            u64 n2 = g1 ? f1 : (g2 ? x : f2);
            u64 n1 = g0 ? f0 : (g1 ? x : f1);
            u64 n0 = g0 ? x  : f0;
            f0 = n0; f1 = n1; f2 = n2; f3 = n3;
        }
        const float gcx = (t0 + t2) * 0.5f;
        const float gcy = (t1 + t3) * 0.5f;
        const float4* __restrict__ pv =
            (const float4*)(rois + ((size_t)(2 * b + 1)) * P * 4);
        float4* __restrict__ o4 = (float4*)out;

        u64 ks[KTOP] = {f0, f1, f2, f3};
        #pragma unroll
        for (int k = 0; k < KTOP; ++k) {
            int idx = (int)(~(u32)ks[k]) & (P - 1);       // decode original prior index
            float4 q = pv[idx];
            float pcx = (q.x + q.z) * 0.5f;
            float pcy = (q.y + q.w) * 0.5f;
            float pw  = q.z - q.x;
            float ph  = q.w - q.y;
            float4 r;
            r.x = (gcx - pcx) / (0.1f * pw);
            r.y = (gcy - pcy) / (0.1f * ph);
            r.z = logf(gw / pw) / 0.2f;
            r.w = logf(gh / ph) / 0.2f;
            o4[((size_t)(b * NG + g)) * KTOP + k] = r;
        }
    }
}

extern "C" void kernel_launch(void* const* d_in, const int* in_sizes, int n_in,
                              void* d_out, int out_size, void* d_ws, size_t ws_size,
                              hipStream_t stream) {
    const float* rois    = (const float*)d_in[0];
    const float* targets = (const float*)d_in[1];
    float* out = (float*)d_out;

    char* w = (char*)d_ws;
    float4* sbox  = (float4*)(w);                                   // 8 MB
    u32*    sidx  = (u32*)  (w + (size_t)B * P * 16);               // 2 MB
    u32*    cnt   = (u32*)  (w + (size_t)B * P * 20);               // 1 MB
    u32*    off   = (u32*)  (w + (size_t)B * P * 20 + (size_t)B * SUB * NBB * 4);  // 65.6 KB
    u32*    whmax = (u32*)  (w + (size_t)B * P * 20 + (size_t)B * SUB * NBB * 4
                               + (size_t)B * (NBB + 1) * 4);        // 128 B

    hipMemsetAsync(whmax, 0, B * 2 * sizeof(u32), stream);
    k_hist<<<dim3(B * SUB), dim3(256),  0, stream>>>(rois, cnt, whmax);
    k_scan<<<dim3(B),       dim3(1024), 0, stream>>>(cnt, off);
    k_scat<<<dim3(B * SUB), dim3(256),  0, stream>>>(rois, cnt, sbox, sidx);
    k_main<<<dim3(B * NG),  dim3(256),  0, stream>>>(rois, targets, sbox, sidx, off, whmax, out);
}